// Round 15
// baseline (76.750 us; speedup 1.0000x reference)
//
#include <hip/hip_runtime.h>

#define ROWS 8192
#define KDIM 4096
#define NDIM 4096

typedef float f32x4 __attribute__((ext_vector_type(4)));

// ws layout (floats):
//   w01  : [4096][16]        at 0        (65536)   -- k-major, r2 contiguous
//   w23  : [16][4096]        at 65536    (65536)
//   tpart: [nseg][8192][16]  at 131072   (nseg*131072)
//
// R15: R13/R14 verified structure; ONE variable vs R13's xw01: K-split
// 4 -> 16 segments => grid 4096 blocks = 8 blocks/CU = 32 waves/CU (full
// occupancy; was 50%). Loads plain (NT-load confirmed -7..10us poison);
// tw23 keeps R14 NT stores (best measured).

__device__ inline f32x4 fma4(float s, f32x4 w, f32x4 a) {
    a.x = fmaf(s, w.x, a.x);
    a.y = fmaf(s, w.y, a.y);
    a.z = fmaf(s, w.z, a.z);
    a.w = fmaf(s, w.w, a.w);
    return a;
}
__device__ inline f32x4 shfl_xor4(f32x4 v, int m) {
    v.x = __shfl_xor(v.x, m, 64);
    v.y = __shfl_xor(v.y, m, 64);
    v.z = __shfl_xor(v.z, m, 64);
    v.w = __shfl_xor(v.w, m, 64);
    return v;
}

// ---------------------------------------------------------------------------
// Build W01 (4096x16, k-major) and W23 (16x4096) from the TT cores.
// ---------------------------------------------------------------------------
__global__ __launch_bounds__(256) void tt_prep(
    const float* __restrict__ c0, const float* __restrict__ c1,
    const float* __restrict__ c2, const float* __restrict__ c3,
    float* __restrict__ w01, float* __restrict__ w23)
{
    int gid = blockIdx.x * 256 + threadIdx.x;  // 0..131071
    if (gid < 65536) {
        int p = gid >> 4, r2 = gid & 15;
        int n0 = p >> 6, n1 = p & 63;
        float s = 0.f;
        #pragma unroll
        for (int r1 = 0; r1 < 16; ++r1)
            s = fmaf(c0[n0 * 16 + r1], c1[(r1 * 64 + n1) * 16 + r2], s);
        w01[gid] = s;
    } else {
        int g = gid - 65536;
        int r2 = g >> 12, j = g & 4095;
        int n2 = j >> 6, n3 = j & 63;
        float s = 0.f;
        #pragma unroll
        for (int r3 = 0; r3 < 16; ++r3)
            s = fmaf(c2[(r2 * 64 + n2) * 16 + r3], c3[r3 * 64 + n3], s);
        w23[g] = s;
    }
}

// ---------------------------------------------------------------------------
// T = x @ W01 -> tpart[seg][row][16].  R5/R13-verified broadcast form,
// plain cached loads. Template SEGK; grid (256, KDIM/SEGK).
// ---------------------------------------------------------------------------
template <int SEGK>
__global__ __launch_bounds__(256) void tt_xw01(
    const float* __restrict__ x, const float* __restrict__ w01,
    float* __restrict__ tpart)
{
    const int t = threadIdx.x;
    const int lane = t & 63;
    const int wv = t >> 6;
    const int q = lane & 3;
    const int klane = lane >> 2;
    const int row0 = blockIdx.x * 32 + wv * 8;
    const int seg = blockIdx.y;
    const int k0 = seg * SEGK;

    const float* xb = x + (size_t)row0 * KDIM + k0;
    const float* wb = w01 + (size_t)k0 * 16;

    f32x4 acc[8];
    #pragma unroll
    for (int r = 0; r < 8; ++r) acc[r] = (f32x4)(0.f);

    #pragma unroll 2
    for (int it = 0; it < SEGK / 64; ++it) {
        const int kk0 = it * 64 + klane * 4;
        f32x4 wq[4];
        #pragma unroll
        for (int kk = 0; kk < 4; ++kk)
            wq[kk] = *(const f32x4*)&wb[(size_t)(kk0 + kk) * 16 + q * 4];
        f32x4 xv[8];
        #pragma unroll
        for (int r = 0; r < 8; ++r)
            xv[r] = *(const f32x4*)&xb[(size_t)r * KDIM + kk0];
        #pragma unroll
        for (int kk = 0; kk < 4; ++kk)
            #pragma unroll
            for (int r = 0; r < 8; ++r)
                acc[r] = fma4(xv[r][kk], wq[kk], acc[r]);
    }

    const bool b5 = lane & 32, b4 = lane & 16, b3 = lane & 8;
    f32x4 s1[4];
    #pragma unroll
    for (int j = 0; j < 4; ++j) {
        f32x4 send = b5 ? acc[j] : acc[4 + j];
        f32x4 keep = b5 ? acc[4 + j] : acc[j];
        s1[j] = keep + shfl_xor4(send, 32);
    }
    f32x4 s2[2];
    #pragma unroll
    for (int j = 0; j < 2; ++j) {
        f32x4 send = b4 ? s1[j] : s1[2 + j];
        f32x4 keep = b4 ? s1[2 + j] : s1[j];
        s2[j] = keep + shfl_xor4(send, 16);
    }
    f32x4 s3;
    {
        f32x4 send = b3 ? s2[0] : s2[1];
        f32x4 keep = b3 ? s2[1] : s2[0];
        s3 = keep + shfl_xor4(send, 8);
    }
    s3 += shfl_xor4(s3, 4);

    if ((lane & 4) == 0) {
        int row = (lane >> 3) & 7;
        float* tp = tpart + ((size_t)seg * ROWS + row0 + row) * 16 + q * 4;
        *(f32x4*)tp = s3;
    }
}

// ---------------------------------------------------------------------------
// out = T @ W23.  R5-verified: 16 rows x 1024 cols, grid (512,4).
// NT stores on out (R14, best measured). Runtime nseg partial-sum.
// ---------------------------------------------------------------------------
__global__ __launch_bounds__(256) void tt_tw23(
    const float* __restrict__ tpart, const float* __restrict__ w23,
    float* __restrict__ out, int nseg)
{
    __shared__ float ts[16][16];
    int rb = blockIdx.x;
    int jb = blockIdx.y;
    int t = threadIdx.x;
    int i0 = rb * 16;
    {
        int row = t >> 4, r = t & 15;
        float s = 0.f;
        for (int seg = 0; seg < nseg; ++seg)
            s += tpart[((size_t)seg * ROWS + i0 + row) * 16 + r];
        ts[row][r] = s;
    }
    __syncthreads();

    int j0 = jb * 1024 + t * 4;
    f32x4 w[16];
    #pragma unroll
    for (int r = 0; r < 16; ++r)
        w[r] = *(const f32x4*)&w23[r * 4096 + j0];

    #pragma unroll 2
    for (int row = 0; row < 16; ++row) {
        const f32x4* trp = (const f32x4*)&ts[row][0];
        f32x4 t0 = trp[0], t1 = trp[1], t2 = trp[2], t3 = trp[3];
        f32x4 a = (f32x4)(0.f);
        a = fma4(t0.x, w[0],  a); a = fma4(t0.y, w[1],  a);
        a = fma4(t0.z, w[2],  a); a = fma4(t0.w, w[3],  a);
        a = fma4(t1.x, w[4],  a); a = fma4(t1.y, w[5],  a);
        a = fma4(t1.z, w[6],  a); a = fma4(t1.w, w[7],  a);
        a = fma4(t2.x, w[8],  a); a = fma4(t2.y, w[9],  a);
        a = fma4(t2.z, w[10], a); a = fma4(t2.w, w[11], a);
        a = fma4(t3.x, w[12], a); a = fma4(t3.y, w[13], a);
        a = fma4(t3.z, w[14], a); a = fma4(t3.w, w[15], a);
        __builtin_nontemporal_store(a, (f32x4*)&out[(size_t)(i0 + row) * 4096 + j0]);
    }
}

extern "C" void kernel_launch(void* const* d_in, const int* in_sizes, int n_in,
                              void* d_out, int out_size, void* d_ws, size_t ws_size,
                              hipStream_t stream) {
    const float* x  = (const float*)d_in[0];
    const float* c0 = (const float*)d_in[1];
    const float* c1 = (const float*)d_in[2];
    const float* c2 = (const float*)d_in[3];
    const float* c3 = (const float*)d_in[4];
    float* out = (float*)d_out;

    float* w01   = (float*)d_ws;
    float* w23   = w01 + 65536;
    float* tpart = w23 + 65536;

    const size_t f = sizeof(float);
    int nseg;
    if      (ws_size >= (size_t)(131072 + 16 * 131072) * f) nseg = 16;
    else if (ws_size >= (size_t)(131072 +  8 * 131072) * f) nseg = 8;
    else                                                    nseg = 4;

    tt_prep<<<512, 256, 0, stream>>>(c0, c1, c2, c3, w01, w23);
    if (nseg == 16)
        tt_xw01<256><<<dim3(256, 16), 256, 0, stream>>>(x, w01, tpart);
    else if (nseg == 8)
        tt_xw01<512><<<dim3(256, 8), 256, 0, stream>>>(x, w01, tpart);
    else
        tt_xw01<1024><<<dim3(256, 4), 256, 0, stream>>>(x, w01, tpart);
    tt_tw23<<<dim3(512, 4), 256, 0, stream>>>(tpart, w23, out, nseg);
}

// Round 16
// 72.350 us; speedup vs baseline: 1.0608x; 1.0608x over previous
//
#include <hip/hip_runtime.h>

#define ROWS 8192
#define KDIM 4096
#define NDIM 4096
#define NSEG 8
#define SEGK 512   // KDIM / NSEG

typedef float f32x4 __attribute__((ext_vector_type(4)));

// ws layout (floats):
//   w01  : [4096][16]        at 0        (65536)   -- k-major, r2 contiguous
//   w23  : [16][4096]        at 65536    (65536)
//   tpart: [NSEG][8192][16]  at 131072   (NSEG*131072 = 4 MB @ NSEG=8)
//
// R16: R14 base (68.9us best). ONE lever: xw01 occupancy 4->8 waves/SIMD
// via kseg 4->8 (grid 2048 blocks). Confound removed: tw23's partial-sum
// is template-unrolled (8 independent loads, not a serial runtime loop).

__device__ inline f32x4 fma4(float s, f32x4 w, f32x4 a) {
    a.x = fmaf(s, w.x, a.x);
    a.y = fmaf(s, w.y, a.y);
    a.z = fmaf(s, w.z, a.z);
    a.w = fmaf(s, w.w, a.w);
    return a;
}
__device__ inline f32x4 shfl_xor4(f32x4 v, int m) {
    v.x = __shfl_xor(v.x, m, 64);
    v.y = __shfl_xor(v.y, m, 64);
    v.z = __shfl_xor(v.z, m, 64);
    v.w = __shfl_xor(v.w, m, 64);
    return v;
}

// ---------------------------------------------------------------------------
// Build W01 (4096x16, k-major) and W23 (16x4096) from the TT cores.
// ---------------------------------------------------------------------------
__global__ __launch_bounds__(256) void tt_prep(
    const float* __restrict__ c0, const float* __restrict__ c1,
    const float* __restrict__ c2, const float* __restrict__ c3,
    float* __restrict__ w01, float* __restrict__ w23)
{
    int gid = blockIdx.x * 256 + threadIdx.x;  // 0..131071
    if (gid < 65536) {
        int p = gid >> 4, r2 = gid & 15;
        int n0 = p >> 6, n1 = p & 63;
        float s = 0.f;
        #pragma unroll
        for (int r1 = 0; r1 < 16; ++r1)
            s = fmaf(c0[n0 * 16 + r1], c1[(r1 * 64 + n1) * 16 + r2], s);
        w01[gid] = s;
    } else {
        int g = gid - 65536;
        int r2 = g >> 12, j = g & 4095;
        int n2 = j >> 6, n3 = j & 63;
        float s = 0.f;
        #pragma unroll
        for (int r3 = 0; r3 < 16; ++r3)
            s = fmaf(c2[(r2 * 64 + n2) * 16 + r3], c3[r3 * 64 + n3], s);
        w23[g] = s;
    }
}

// ---------------------------------------------------------------------------
// T = x @ W01 -> tpart[seg][row][16].  R5/R13-verified broadcast form,
// plain cached loads, unroll 2 (VGPR ~52 -> 8 waves/SIMD possible).
// Grid (256 rowblocks, 8 ksegs) = 2048 blocks = 8 blocks/CU.
// ---------------------------------------------------------------------------
__global__ __launch_bounds__(256) void tt_xw01(
    const float* __restrict__ x, const float* __restrict__ w01,
    float* __restrict__ tpart)
{
    const int t = threadIdx.x;
    const int lane = t & 63;
    const int wv = t >> 6;
    const int q = lane & 3;
    const int klane = lane >> 2;
    const int row0 = blockIdx.x * 32 + wv * 8;
    const int seg = blockIdx.y;
    const int k0 = seg * SEGK;

    const float* xb = x + (size_t)row0 * KDIM + k0;
    const float* wb = w01 + (size_t)k0 * 16;

    f32x4 acc[8];
    #pragma unroll
    for (int r = 0; r < 8; ++r) acc[r] = (f32x4)(0.f);

    #pragma unroll 2
    for (int it = 0; it < SEGK / 64; ++it) {
        const int kk0 = it * 64 + klane * 4;
        f32x4 wq[4];
        #pragma unroll
        for (int kk = 0; kk < 4; ++kk)
            wq[kk] = *(const f32x4*)&wb[(size_t)(kk0 + kk) * 16 + q * 4];
        f32x4 xv[8];
        #pragma unroll
        for (int r = 0; r < 8; ++r)
            xv[r] = *(const f32x4*)&xb[(size_t)r * KDIM + kk0];
        #pragma unroll
        for (int kk = 0; kk < 4; ++kk)
            #pragma unroll
            for (int r = 0; r < 8; ++r)
                acc[r] = fma4(xv[r][kk], wq[kk], acc[r]);
    }

    const bool b5 = lane & 32, b4 = lane & 16, b3 = lane & 8;
    f32x4 s1[4];
    #pragma unroll
    for (int j = 0; j < 4; ++j) {
        f32x4 send = b5 ? acc[j] : acc[4 + j];
        f32x4 keep = b5 ? acc[4 + j] : acc[j];
        s1[j] = keep + shfl_xor4(send, 32);
    }
    f32x4 s2[2];
    #pragma unroll
    for (int j = 0; j < 2; ++j) {
        f32x4 send = b4 ? s1[j] : s1[2 + j];
        f32x4 keep = b4 ? s1[2 + j] : s1[j];
        s2[j] = keep + shfl_xor4(send, 16);
    }
    f32x4 s3;
    {
        f32x4 send = b3 ? s2[0] : s2[1];
        f32x4 keep = b3 ? s2[1] : s2[0];
        s3 = keep + shfl_xor4(send, 8);
    }
    s3 += shfl_xor4(s3, 4);

    if ((lane & 4) == 0) {
        int row = (lane >> 3) & 7;
        float* tp = tpart + ((size_t)seg * ROWS + row0 + row) * 16 + q * 4;
        *(f32x4*)tp = s3;
    }
}

// ---------------------------------------------------------------------------
// out = T @ W23.  R5-verified: 16 rows x 1024 cols, grid (512,4).
// NT stores on out (R14). Partial-sum fully unrolled at compile time.
// ---------------------------------------------------------------------------
__global__ __launch_bounds__(256) void tt_tw23(
    const float* __restrict__ tpart, const float* __restrict__ w23,
    float* __restrict__ out)
{
    __shared__ float ts[16][16];
    int rb = blockIdx.x;
    int jb = blockIdx.y;
    int t = threadIdx.x;
    int i0 = rb * 16;
    {
        int row = t >> 4, r = t & 15;
        float s = 0.f;
        #pragma unroll
        for (int seg = 0; seg < NSEG; ++seg)       // compile-time: 8 indep loads
            s += tpart[((size_t)seg * ROWS + i0 + row) * 16 + r];
        ts[row][r] = s;
    }
    __syncthreads();

    int j0 = jb * 1024 + t * 4;
    f32x4 w[16];
    #pragma unroll
    for (int r = 0; r < 16; ++r)
        w[r] = *(const f32x4*)&w23[r * 4096 + j0];

    #pragma unroll 2
    for (int row = 0; row < 16; ++row) {
        const f32x4* trp = (const f32x4*)&ts[row][0];
        f32x4 t0 = trp[0], t1 = trp[1], t2 = trp[2], t3 = trp[3];
        f32x4 a = (f32x4)(0.f);
        a = fma4(t0.x, w[0],  a); a = fma4(t0.y, w[1],  a);
        a = fma4(t0.z, w[2],  a); a = fma4(t0.w, w[3],  a);
        a = fma4(t1.x, w[4],  a); a = fma4(t1.y, w[5],  a);
        a = fma4(t1.z, w[6],  a); a = fma4(t1.w, w[7],  a);
        a = fma4(t2.x, w[8],  a); a = fma4(t2.y, w[9],  a);
        a = fma4(t2.z, w[10], a); a = fma4(t2.w, w[11], a);
        a = fma4(t3.x, w[12], a); a = fma4(t3.y, w[13], a);
        a = fma4(t3.z, w[14], a); a = fma4(t3.w, w[15], a);
        __builtin_nontemporal_store(a, (f32x4*)&out[(size_t)(i0 + row) * 4096 + j0]);
    }
}

extern "C" void kernel_launch(void* const* d_in, const int* in_sizes, int n_in,
                              void* d_out, int out_size, void* d_ws, size_t ws_size,
                              hipStream_t stream) {
    const float* x  = (const float*)d_in[0];
    const float* c0 = (const float*)d_in[1];
    const float* c1 = (const float*)d_in[2];
    const float* c2 = (const float*)d_in[3];
    const float* c3 = (const float*)d_in[4];
    float* out = (float*)d_out;

    float* w01   = (float*)d_ws;
    float* w23   = w01 + 65536;
    float* tpart = w23 + 65536;   // NSEG*131072 floats = 4 MB (ws-verified: R15 used 8.9 MB)

    tt_prep<<<512, 256, 0, stream>>>(c0, c1, c2, c3, w01, w23);
    tt_xw01<<<dim3(256, NSEG), 256, 0, stream>>>(x, w01, tpart);
    tt_tw23<<<dim3(512, 4), 256, 0, stream>>>(tpart, w23, out);
}

// Round 17
// 59.981 us; speedup vs baseline: 1.2796x; 1.2062x over previous
//
#include <hip/hip_runtime.h>

#define ROWS 8192
#define KDIM 4096
#define NDIM 4096

typedef float f32x4 __attribute__((ext_vector_type(4)));

// ws layout (floats):
//   w01 : [4096][16]  at 0      (65536)   -- k-major, r2 contiguous
//   w23 : [16][4096]  at 65536  (65536)
//
// R17: single fused kernel. Phase 1 = R5-verified broadcast engine (q=lane&3,
// klane=lane>>2, butterfly reduce), 4 waves K-split 4x1024, partials summed
// in LDS. Phase 2 = R5-verified tw23 j-sweep (w[16] regs, NT stores).
// Eliminates tpart traffic + 3rd launch; read & write streams overlap
// across blocks. Grid 1024 = 4 blocks/CU.

__device__ inline f32x4 fma4(float s, f32x4 w, f32x4 a) {
    a.x = fmaf(s, w.x, a.x);
    a.y = fmaf(s, w.y, a.y);
    a.z = fmaf(s, w.z, a.z);
    a.w = fmaf(s, w.w, a.w);
    return a;
}
__device__ inline f32x4 shfl_xor4(f32x4 v, int m) {
    v.x = __shfl_xor(v.x, m, 64);
    v.y = __shfl_xor(v.y, m, 64);
    v.z = __shfl_xor(v.z, m, 64);
    v.w = __shfl_xor(v.w, m, 64);
    return v;
}

// ---------------------------------------------------------------------------
// Build W01 (4096x16, k-major) and W23 (16x4096) from the TT cores.
// ---------------------------------------------------------------------------
__global__ __launch_bounds__(256) void tt_prep(
    const float* __restrict__ c0, const float* __restrict__ c1,
    const float* __restrict__ c2, const float* __restrict__ c3,
    float* __restrict__ w01, float* __restrict__ w23)
{
    int gid = blockIdx.x * 256 + threadIdx.x;  // 0..131071
    if (gid < 65536) {
        int p = gid >> 4, r2 = gid & 15;
        int n0 = p >> 6, n1 = p & 63;
        float s = 0.f;
        #pragma unroll
        for (int r1 = 0; r1 < 16; ++r1)
            s = fmaf(c0[n0 * 16 + r1], c1[(r1 * 64 + n1) * 16 + r2], s);
        w01[gid] = s;
    } else {
        int g = gid - 65536;
        int r2 = g >> 12, j = g & 4095;
        int n2 = j >> 6, n3 = j & 63;
        float s = 0.f;
        #pragma unroll
        for (int r3 = 0; r3 < 16; ++r3)
            s = fmaf(c2[(r2 * 64 + n2) * 16 + r3], c3[r3 * 64 + n3], s);
        w23[g] = s;
    }
}

// ---------------------------------------------------------------------------
// Fused: out[8 rows] = (x[8 rows] @ W01) @ W23 per block. Grid 1024.
// ---------------------------------------------------------------------------
__global__ __launch_bounds__(256) void tt_fused(
    const float* __restrict__ x, const float* __restrict__ w01,
    const float* __restrict__ w23, float* __restrict__ out)
{
    __shared__ __align__(16) float tsp[4][8][16];  // per-wave partial T
    __shared__ __align__(16) float ts[8][16];      // summed T tile
    const int t = threadIdx.x;
    const int lane = t & 63;
    const int wv = t >> 6;            // wave 0..3: K segment owner
    const int q = lane & 3;           // r2 quad
    const int klane = lane >> 2;      // 0..15
    const int row0 = blockIdx.x * 8;
    const int k0 = wv * 1024;

    const float* xb = x + (size_t)row0 * KDIM + k0;
    const float* wb = w01 + (size_t)k0 * 16;

    // ---- Phase 1: R5-verified broadcast engine, 8 rows x 1024 k per wave.
    f32x4 acc[8];
    #pragma unroll
    for (int r = 0; r < 8; ++r) acc[r] = (f32x4)(0.f);

    #pragma unroll 2
    for (int it = 0; it < 1024 / 64; ++it) {
        const int kk0 = it * 64 + klane * 4;
        f32x4 wq[4];
        #pragma unroll
        for (int kk = 0; kk < 4; ++kk)
            wq[kk] = *(const f32x4*)&wb[(size_t)(kk0 + kk) * 16 + q * 4];
        f32x4 xv[8];
        #pragma unroll
        for (int r = 0; r < 8; ++r)
            xv[r] = *(const f32x4*)&xb[(size_t)r * KDIM + kk0];
        #pragma unroll
        for (int kk = 0; kk < 4; ++kk)
            #pragma unroll
            for (int r = 0; r < 8; ++r)
                acc[r] = fma4(xv[r][kk], wq[kk], acc[r]);
    }

    // R5-verified reduce-scatter butterfly over klane (static indices only).
    const bool b5 = lane & 32, b4 = lane & 16, b3 = lane & 8;
    f32x4 s1[4];
    #pragma unroll
    for (int j = 0; j < 4; ++j) {
        f32x4 send = b5 ? acc[j] : acc[4 + j];
        f32x4 keep = b5 ? acc[4 + j] : acc[j];
        s1[j] = keep + shfl_xor4(send, 32);
    }
    f32x4 s2[2];
    #pragma unroll
    for (int j = 0; j < 2; ++j) {
        f32x4 send = b4 ? s1[j] : s1[2 + j];
        f32x4 keep = b4 ? s1[2 + j] : s1[j];
        s2[j] = keep + shfl_xor4(send, 16);
    }
    f32x4 s3;
    {
        f32x4 send = b3 ? s2[0] : s2[1];
        f32x4 keep = b3 ? s2[1] : s2[0];
        s3 = keep + shfl_xor4(send, 8);
    }
    s3 += shfl_xor4(s3, 4);

    if ((lane & 4) == 0) {
        int row = (lane >> 3) & 7;
        *(f32x4*)&tsp[wv][row][q * 4] = s3;
    }
    __syncthreads();

    // Sum the 4 wave partials into ts[8][16].
    if (t < 128) {
        int row = t >> 4, r = t & 15;
        ts[row][r] = tsp[0][row][r] + tsp[1][row][r]
                   + tsp[2][row][r] + tsp[3][row][r];
    }
    __syncthreads();

    // ---- Phase 2: R5-verified j-sweep. 4 j-tiles of 1024; w[16] in regs.
    const size_t obase = (size_t)row0 * NDIM;
    #pragma unroll 1
    for (int jt = 0; jt < 4; ++jt) {
        const int j0 = jt * 1024 + t * 4;
        f32x4 w[16];
        #pragma unroll
        for (int r = 0; r < 16; ++r)
            w[r] = *(const f32x4*)&w23[r * NDIM + j0];
        #pragma unroll 2
        for (int row = 0; row < 8; ++row) {
            const f32x4* trp = (const f32x4*)&ts[row][0];
            f32x4 t0 = trp[0], t1 = trp[1], t2 = trp[2], t3 = trp[3];
            f32x4 a = (f32x4)(0.f);
            a = fma4(t0.x, w[0],  a); a = fma4(t0.y, w[1],  a);
            a = fma4(t0.z, w[2],  a); a = fma4(t0.w, w[3],  a);
            a = fma4(t1.x, w[4],  a); a = fma4(t1.y, w[5],  a);
            a = fma4(t1.z, w[6],  a); a = fma4(t1.w, w[7],  a);
            a = fma4(t2.x, w[8],  a); a = fma4(t2.y, w[9],  a);
            a = fma4(t2.z, w[10], a); a = fma4(t2.w, w[11], a);
            a = fma4(t3.x, w[12], a); a = fma4(t3.y, w[13], a);
            a = fma4(t3.z, w[14], a); a = fma4(t3.w, w[15], a);
            __builtin_nontemporal_store(a,
                (f32x4*)&out[obase + (size_t)row * NDIM + j0]);
        }
    }
}

extern "C" void kernel_launch(void* const* d_in, const int* in_sizes, int n_in,
                              void* d_out, int out_size, void* d_ws, size_t ws_size,
                              hipStream_t stream) {
    const float* x  = (const float*)d_in[0];
    const float* c0 = (const float*)d_in[1];
    const float* c1 = (const float*)d_in[2];
    const float* c2 = (const float*)d_in[3];
    const float* c3 = (const float*)d_in[4];
    float* out = (float*)d_out;

    float* w01 = (float*)d_ws;
    float* w23 = w01 + 65536;

    tt_prep<<<512, 256, 0, stream>>>(c0, c1, c2, c3, w01, w23);
    tt_fused<<<1024, 256, 0, stream>>>(x, w01, w23, out);
}